// Round 1
// baseline (421.264 us; speedup 1.0000x reference)
//
#include <hip/hip_runtime.h>

typedef __attribute__((ext_vector_type(8))) short short8;
typedef __attribute__((ext_vector_type(4))) float f32x4;

#define HID 256
#define BATCH 65536

__device__ inline ushort bf16u(float f) {
  unsigned u = __builtin_bit_cast(unsigned, f);
  u = (u + 0x7FFFu + ((u >> 16) & 1u)) >> 16;
  return (ushort)u;
}
__device__ inline unsigned packbf2(float a, float b) {
  unsigned ua = __builtin_bit_cast(unsigned, a);
  unsigned ub = __builtin_bit_cast(unsigned, b);
  ua = (ua + 0x7FFFu + ((ua >> 16) & 1u)) >> 16;
  ub = (ub + 0x7FFFu + ((ub >> 16) & 1u)) >> 16;
  return ua | (ub << 16);
}
__device__ inline short8 cvt8(float4 a, float4 b) {
  union { short8 v; unsigned u[4]; } r;
  r.u[0] = packbf2(a.x, a.y);
  r.u[1] = packbf2(a.z, a.w);
  r.u[2] = packbf2(b.x, b.y);
  r.u[3] = packbf2(b.z, b.w);
  return r.v;
}

// ---------------- prep kernels ----------------
__global__ void prep_lambda(const float* __restrict__ nu, const float* __restrict__ th,
                            float* __restrict__ lam) {
  int i = threadIdx.x;  // 256 threads
  float mag = __expf(-__expf(nu[i]));
  float ang = __expf(th[i]);
  lam[i] = mag * __cosf(ang);
  lam[HID + i] = mag * __sinf(ang);
}

// Pack weights into MFMA B-fragment order (bf16):
//   entry index = ((ntile*KS + ks)*64 + lane), 8 bf16 per entry
//   value[j] = W[ks*32 + (lane>>4)*8 + j][ntile*16 + (lane&15)]
__global__ void prep_weights(const float* __restrict__ gl, const float* __restrict__ Br,
                             const float* __restrict__ Bi, const float* __restrict__ Cr,
                             const float* __restrict__ Ci, ushort* __restrict__ wbr,
                             ushort* __restrict__ wbi, ushort* __restrict__ wcc) {
  int t = blockIdx.x * 256 + threadIdx.x;  // 0..32767
  int lane = t & 63;
  int l15 = lane & 15, quad = lane >> 4;
  union { ushort s[8]; uint4 q; } r;
  if (t < 16384) {
    const float* B = (t < 8192) ? Br : Bi;
    ushort* w = (t < 8192) ? wbr : wbi;
    int e = t & 8191;
    int ntile = e >> 9;        // e / (8*64)
    int ks = (e >> 6) & 7;
    int n = ntile * 16 + l15;
    int k0 = ks * 32 + quad * 8;
    float g = __expf(gl[n]);
#pragma unroll
    for (int j = 0; j < 8; ++j) r.s[j] = bf16u(B[(k0 + j) * HID + n] * g);
    *(uint4*)(w + (size_t)e * 8) = r.q;
  } else {
    int e = t - 16384;         // 0..16383
    int ntile = e >> 10;       // e / (16*64)
    int ks = (e >> 6) & 15;
    int n = ntile * 16 + l15;
    int k0 = ks * 32 + quad * 8;
#pragma unroll
    for (int j = 0; j < 8; ++j) {
      int k = k0 + j;
      float v = (k < 256) ? Cr[k * HID + n] : -Ci[(k - 256) * HID + n];
      r.s[j] = bf16u(v);
    }
    *(uint4*)(wcc + (size_t)e * 8) = r.q;
  }
}

// ---------------- main fused kernel ----------------
// 64 rows/block, 4 waves split 256 cols (64 cols each).
__global__ __launch_bounds__(256, 2) void lru_main(
    const float* __restrict__ xr_in, const float* __restrict__ xi_in,
    const float* __restrict__ u_in, const float* __restrict__ Dv,
    const float* __restrict__ lam, const ushort* __restrict__ wbr,
    const ushort* __restrict__ wbi, const ushort* __restrict__ wcc,
    float* __restrict__ out) {
  __shared__ ushort xk[64 * 520];  // [m][k], k in [0,512), stride 520 (2-way-free banks)

  const int tid = threadIdx.x;
  const int lane = tid & 63;
  const int wave = tid >> 6;
  const int l15 = lane & 15;
  const int quad = lane >> 4;
  const int row0 = blockIdx.x << 6;
  const int col0 = wave << 6;

  // ---- Stage A: uB_r, uB_i = u @ (B*gamma) ----
  f32x4 accR[4][4], accI[4][4];
#pragma unroll
  for (int i = 0; i < 4; ++i)
#pragma unroll
    for (int j = 0; j < 4; ++j)
#pragma unroll
      for (int r = 0; r < 4; ++r) { accR[i][j][r] = 0.f; accI[i][j][r] = 0.f; }

  for (int ks = 0; ks < 8; ++ks) {
    short8 a[4];
#pragma unroll
    for (int rt = 0; rt < 4; ++rt) {
      const float* up = u_in + (size_t)(row0 + rt * 16 + l15) * HID + (ks * 32 + quad * 8);
      float4 f0 = *(const float4*)up;
      float4 f1 = *(const float4*)(up + 4);
      a[rt] = cvt8(f0, f1);
    }
    short8 br[4], bi[4];
#pragma unroll
    for (int ct = 0; ct < 4; ++ct) {
      int off = (((wave * 4 + ct) * 8 + ks) * 64 + lane) * 8;
      br[ct] = *(const short8*)(wbr + off);
      bi[ct] = *(const short8*)(wbi + off);
    }
#pragma unroll
    for (int rt = 0; rt < 4; ++rt)
#pragma unroll
      for (int ct = 0; ct < 4; ++ct) {
        accR[rt][ct] = __builtin_amdgcn_mfma_f32_16x16x32_bf16(a[rt], br[ct], accR[rt][ct], 0, 0, 0);
        accI[rt][ct] = __builtin_amdgcn_mfma_f32_16x16x32_bf16(a[rt], bi[ct], accI[rt][ct], 0, 0, 0);
      }
  }

  // ---- Elementwise: x_k = Lambda*x + uB ; write fp32 out + bf16 LDS; y-acc = D*u ----
  float lr[4], li[4], dd[4];
#pragma unroll
  for (int ct = 0; ct < 4; ++ct) {
    int n = col0 + ct * 16 + l15;
    lr[ct] = lam[n];
    li[ct] = lam[HID + n];
    dd[ct] = Dv[n];
  }
  f32x4 accY[4][4];
#pragma unroll
  for (int rt = 0; rt < 4; ++rt)
#pragma unroll
    for (int ct = 0; ct < 4; ++ct) {
      int n = col0 + ct * 16 + l15;
#pragma unroll
      for (int r = 0; r < 4; ++r) {
        int m = rt * 16 + quad * 4 + r;
        int idx = (row0 + m) * HID + n;
        float xr = xr_in[idx];
        float xi = xi_in[idx];
        float nr = lr[ct] * xr - li[ct] * xi + accR[rt][ct][r];
        float ni = lr[ct] * xi + li[ct] * xr + accI[rt][ct][r];
        out[idx] = nr;
        out[16777216 + idx] = ni;
        accY[rt][ct][r] = dd[ct] * u_in[idx];
        xk[m * 520 + n] = bf16u(nr);
        xk[m * 520 + 256 + n] = bf16u(ni);
      }
    }
  __syncthreads();

  // ---- Stage B: y = [xkr|xki] @ [Cr; -Ci] + D*u ----
  for (int ks = 0; ks < 16; ++ks) {
    short8 a[4];
#pragma unroll
    for (int rt = 0; rt < 4; ++rt)
      a[rt] = *(const short8*)&xk[(rt * 16 + l15) * 520 + ks * 32 + quad * 8];
    short8 b[4];
#pragma unroll
    for (int ct = 0; ct < 4; ++ct) {
      int off = (((wave * 4 + ct) * 16 + ks) * 64 + lane) * 8;
      b[ct] = *(const short8*)(wcc + off);
    }
#pragma unroll
    for (int rt = 0; rt < 4; ++rt)
#pragma unroll
      for (int ct = 0; ct < 4; ++ct)
        accY[rt][ct] = __builtin_amdgcn_mfma_f32_16x16x32_bf16(a[rt], b[ct], accY[rt][ct], 0, 0, 0);
  }
#pragma unroll
  for (int rt = 0; rt < 4; ++rt)
#pragma unroll
    for (int ct = 0; ct < 4; ++ct) {
      int n = col0 + ct * 16 + l15;
#pragma unroll
      for (int r = 0; r < 4; ++r) {
        int m = rt * 16 + quad * 4 + r;
        int idx = (row0 + m) * HID + n;
        out[33554432 + idx] = accY[rt][ct][r];
      }
    }
}

extern "C" void kernel_launch(void* const* d_in, const int* in_sizes, int n_in,
                              void* d_out, int out_size, void* d_ws, size_t ws_size,
                              hipStream_t stream) {
  const float* x_real = (const float*)d_in[0];
  const float* x_imag = (const float*)d_in[1];
  const float* u_k = (const float*)d_in[2];
  const float* nu_log = (const float*)d_in[3];
  const float* theta_log = (const float*)d_in[4];
  const float* gamma_log = (const float*)d_in[5];
  const float* B_real = (const float*)d_in[6];
  const float* B_img = (const float*)d_in[7];
  const float* C_real = (const float*)d_in[8];
  const float* C_img = (const float*)d_in[9];
  const float* Dv = (const float*)d_in[10];

  // ws layout: [0,2048) lam fp32[512] | [2048,133120) wbr | [133120,264192) wbi
  //            | [264192,526336) wc   (bf16 fragment-shuffled)
  float* lam = (float*)d_ws;
  ushort* wbr = (ushort*)d_ws + 1024;
  ushort* wbi = wbr + 65536;
  ushort* wcc = wbi + 65536;

  prep_lambda<<<1, 256, 0, stream>>>(nu_log, theta_log, lam);
  prep_weights<<<128, 256, 0, stream>>>(gamma_log, B_real, B_img, C_real, C_img, wbr, wbi, wcc);
  lru_main<<<BATCH / 64, 256, 0, stream>>>(x_real, x_imag, u_k, Dv, lam, wbr, wbi, wcc,
                                           (float*)d_out);
}